// Round 1
// baseline (1421.871 us; speedup 1.0000x reference)
//
#include <hip/hip_runtime.h>
#include <math.h>

#define TB 2048
#define CC 1024
#define NH 16
#define HD 64

typedef __bf16 bf16x8 __attribute__((ext_vector_type(8)));
typedef __bf16 bf16x4 __attribute__((ext_vector_type(4)));
typedef float  f32x4  __attribute__((ext_vector_type(4)));

// ---------------------------------------------------------------------------
// Tiled bf16-MFMA GEMM: C[M,N] = A[M,K] (fp32) * B[K,N] (fp32) + bias[N]
// Tile 128x128, BK=32, 256 threads (4 waves in 2x2), fp32 accum.
// MODE 0: epilogue splits qkv into q/k/v [B,H,T,D] ws, fake-quant on k,v.
// MODE 1: plain bias + store row-major to out0.
// ---------------------------------------------------------------------------
template<int MODE>
__global__ __launch_bounds__(256)
void gemm_kernel(const float* __restrict__ A, const float* __restrict__ B,
                 const float* __restrict__ bias,
                 float* __restrict__ out0, float* __restrict__ out1,
                 float* __restrict__ out2,
                 int M, int N, int K,
                 const float* __restrict__ scp, const float* __restrict__ zpp)
{
    // +8 shorts pad -> row stride 40 shorts = 80B (16B aligned, 20 banks)
    __shared__ __bf16 Asm[128][40];
    __shared__ __bf16 Bsm[128][40];   // transposed: [n][k]

    const int tid  = threadIdx.x;
    const int m0   = blockIdx.y * 128;
    const int n0   = blockIdx.x * 128;
    const int w    = tid >> 6, lane = tid & 63;
    const int wm   = (w & 1) * 64, wn = (w >> 1) * 64;
    const int r16  = lane & 15, quad = lane >> 4;

    f32x4 acc[4][4];
    #pragma unroll
    for (int i = 0; i < 4; i++)
        #pragma unroll
        for (int j = 0; j < 4; j++) acc[i][j] = 0.f;

    for (int k0 = 0; k0 < K; k0 += 32) {
        // ---- stage A tile: 128 rows x 32 cols (8 float4/row, 1024 tasks)
        #pragma unroll
        for (int i = 0; i < 4; i++) {
            int id  = tid + i * 256;
            int row = id >> 3, c = id & 7;
            f32x4 v = *(const f32x4*)&A[(size_t)(m0 + row) * K + k0 + c * 4];
            bf16x4 bv;
            bv.x = (__bf16)v.x; bv.y = (__bf16)v.y;
            bv.z = (__bf16)v.z; bv.w = (__bf16)v.w;
            *(bf16x4*)&Asm[row][c * 4] = bv;
        }
        // ---- stage B tile transposed: [n][k] (coalesced col reads)
        #pragma unroll
        for (int i = 0; i < 4; i++) {
            int id = tid + i * 256;
            int n  = id & 127, kc = id >> 7;   // kc in [0,8)
            float f0 = B[(size_t)(k0 + kc * 4 + 0) * N + n0 + n];
            float f1 = B[(size_t)(k0 + kc * 4 + 1) * N + n0 + n];
            float f2 = B[(size_t)(k0 + kc * 4 + 2) * N + n0 + n];
            float f3 = B[(size_t)(k0 + kc * 4 + 3) * N + n0 + n];
            bf16x4 bv;
            bv.x = (__bf16)f0; bv.y = (__bf16)f1;
            bv.z = (__bf16)f2; bv.w = (__bf16)f3;
            *(bf16x4*)&Bsm[n][kc * 4] = bv;
        }
        __syncthreads();

        bf16x8 af[4], bfr[4];
        #pragma unroll
        for (int mt = 0; mt < 4; mt++)
            af[mt] = *(const bf16x8*)&Asm[wm + mt * 16 + r16][quad * 8];
        #pragma unroll
        for (int nt = 0; nt < 4; nt++)
            bfr[nt] = *(const bf16x8*)&Bsm[wn + nt * 16 + r16][quad * 8];
        #pragma unroll
        for (int mt = 0; mt < 4; mt++)
            #pragma unroll
            for (int nt = 0; nt < 4; nt++)
                acc[mt][nt] = __builtin_amdgcn_mfma_f32_16x16x32_bf16(
                    af[mt], bfr[nt], acc[mt][nt], 0, 0, 0);
        __syncthreads();
    }

    const float sc = scp[0];
    const float zp = zpp[0];

    #pragma unroll
    for (int mt = 0; mt < 4; mt++) {
        #pragma unroll
        for (int nt = 0; nt < 4; nt++) {
            #pragma unroll
            for (int r = 0; r < 4; r++) {
                int gm = m0 + wm + mt * 16 + quad * 4 + r;  // D row
                int gn = n0 + wn + nt * 16 + r16;           // D col
                float val = acc[mt][nt][r] + bias[gn];
                if (MODE == 1) {
                    out0[(size_t)gm * N + gn] = val;
                } else {
                    int part = gn >> 10;        // 0=q 1=k 2=v
                    int idx  = gn & 1023;
                    int h = idx >> 6, d = idx & 63;
                    int b = gm >> 11, t = gm & 2047;
                    size_t off = (((size_t)(b * NH + h)) * TB + t) * HD + d;
                    if (part == 0) {
                        out0[off] = val;
                    } else {
                        float qv = val / sc + zp;
                        qv = rintf(qv);                       // half-to-even
                        qv = fminf(fmaxf(qv, 0.f), 255.f);
                        float dq = (qv - zp) * sc;
                        if (part == 1) out1[off] = dq;
                        else           out2[off] = dq;
                    }
                }
            }
        }
    }
}

// ---------------------------------------------------------------------------
// Flash attention, fp32. One thread per query row. Block = 256 threads
// handles 256 consecutive q rows of one (b,h). Grid = B*H*(T/256) = 256.
// K/V staged in 64-key LDS tiles; broadcast reads (conflict-free).
// Online softmax processed in 16-key chunks (registers).
// ---------------------------------------------------------------------------
__global__ __launch_bounds__(256)
void attn_kernel(const float* __restrict__ Q, const float* __restrict__ Kk,
                 const float* __restrict__ V, float* __restrict__ O)
{
    __shared__ float Ksm[64][64];
    __shared__ float Vsm[64][64];

    const int tid = threadIdx.x;
    const int bh  = blockIdx.x >> 3;
    const int q0  = (blockIdx.x & 7) << 8;
    const int tq  = q0 + tid;
    const int b   = bh >> 4, h = bh & 15;

    const float* Qrow = Q + ((size_t)bh * TB + tq) * HD;
    float q[64], o[64];
    #pragma unroll
    for (int i = 0; i < 16; i++) {
        f32x4 v = *(const f32x4*)&Qrow[i * 4];
        q[i*4+0] = v.x; q[i*4+1] = v.y; q[i*4+2] = v.z; q[i*4+3] = v.w;
    }
    #pragma unroll
    for (int d = 0; d < 64; d++) o[d] = 0.f;
    float mrun = -3.0e38f, lrun = 0.f;

    const int ktmax = (q0 + 255) >> 6;
    for (int kt = 0; kt <= ktmax; kt++) {
        const float* Kt = Kk + ((size_t)bh * TB + kt * 64) * HD;
        const float* Vt = V  + ((size_t)bh * TB + kt * 64) * HD;
        #pragma unroll
        for (int i = 0; i < 4; i++) {
            int id = tid + i * 256;
            int row = id >> 4, c = id & 15;
            *(f32x4*)&Ksm[row][c * 4] = *(const f32x4*)&Kt[row * 64 + c * 4];
            *(f32x4*)&Vsm[row][c * 4] = *(const f32x4*)&Vt[row * 64 + c * 4];
        }
        __syncthreads();

        int nk = tq - kt * 64 + 1;
        if (nk > 64) nk = 64;

        for (int c = 0; c < 4 && c * 16 < nk; c++) {
            float s[16];
            #pragma unroll
            for (int jj = 0; jj < 16; jj++) {
                int j = c * 16 + jj;
                float a0 = 0.f;
                #pragma unroll
                for (int dd = 0; dd < 16; dd++) {
                    f32x4 kv = *(const f32x4*)&Ksm[j][dd * 4];
                    a0 += q[dd*4+0]*kv.x + q[dd*4+1]*kv.y
                        + q[dd*4+2]*kv.z + q[dd*4+3]*kv.w;
                }
                s[jj] = (j < nk) ? a0 * 0.125f : -3.0e38f;
            }
            float cmax = s[0];
            #pragma unroll
            for (int jj = 1; jj < 16; jj++) cmax = fmaxf(cmax, s[jj]);
            float mnew  = fmaxf(mrun, cmax);
            float alpha = __expf(mrun - mnew);
            lrun *= alpha;
            #pragma unroll
            for (int d = 0; d < 64; d++) o[d] *= alpha;
            #pragma unroll
            for (int jj = 0; jj < 16; jj++) {
                int j = c * 16 + jj;
                float p = __expf(s[jj] - mnew);
                lrun += p;
                #pragma unroll
                for (int dd = 0; dd < 16; dd++) {
                    f32x4 vv = *(const f32x4*)&Vsm[j][dd * 4];
                    o[dd*4+0] += p * vv.x; o[dd*4+1] += p * vv.y;
                    o[dd*4+2] += p * vv.z; o[dd*4+3] += p * vv.w;
                }
            }
            mrun = mnew;
        }
        __syncthreads();
    }

    const float inv = 1.f / lrun;
    float* Orow = O + ((size_t)(b * TB) + tq) * CC + h * HD;
    #pragma unroll
    for (int i = 0; i < 16; i++) {
        f32x4 v;
        v.x = o[i*4+0] * inv; v.y = o[i*4+1] * inv;
        v.z = o[i*4+2] * inv; v.w = o[i*4+3] * inv;
        *(f32x4*)&Orow[i * 4] = v;
    }
}

extern "C" void kernel_launch(void* const* d_in, const int* in_sizes, int n_in,
                              void* d_out, int out_size, void* d_ws, size_t ws_size,
                              hipStream_t stream) {
    (void)in_sizes; (void)n_in; (void)out_size; (void)ws_size;
    const float* hidden   = (const float*)d_in[0];
    const float* W_attn   = (const float*)d_in[1];
    const float* b_attn   = (const float*)d_in[2];
    const float* W_proj   = (const float*)d_in[3];
    const float* b_proj   = (const float*)d_in[4];
    const float* kv_scale = (const float*)d_in[5];
    const float* kv_zp    = (const float*)d_in[6];
    float* out = (float*)d_out;

    // workspace: q/k/v [B,H,T,D] fp32 (16MB each) + attn out [B,T,C] (16MB)
    float* qws = (float*)d_ws;
    float* kws = qws + (size_t)2 * NH * TB * HD;
    float* vws = kws + (size_t)2 * NH * TB * HD;
    float* ows = vws + (size_t)2 * NH * TB * HD;

    // 1) QKV GEMM + bias + split + fake-quant(k,v)
    gemm_kernel<0><<<dim3(3072 / 128, 4096 / 128), 256, 0, stream>>>(
        hidden, W_attn, b_attn, qws, kws, vws, 4096, 3072, 1024, kv_scale, kv_zp);

    // 2) causal flash attention -> [B,T,C]
    attn_kernel<<<dim3(2 * NH * (TB / 256)), 256, 0, stream>>>(qws, kws, vws, ows);

    // 3) proj GEMM + bias -> out
    gemm_kernel<1><<<dim3(1024 / 128, 4096 / 128), 256, 0, stream>>>(
        ows, W_proj, b_proj, out, nullptr, nullptr, 4096, 1024, 1024, kv_scale, kv_zp);
}

// Round 2
// 288.054 us; speedup vs baseline: 4.9361x; 4.9361x over previous
//
#include <hip/hip_runtime.h>
#include <math.h>

#define TB 2048
#define CC 1024
#define NH 16
#define HD 64

typedef __bf16 bf16x8 __attribute__((ext_vector_type(8)));
typedef __bf16 bf16x4 __attribute__((ext_vector_type(4)));
typedef float  f32x4  __attribute__((ext_vector_type(4)));

__device__ inline float exp2fast(float x) { return __builtin_amdgcn_exp2f(x); }

// ---------------------------------------------------------------------------
// Tiled bf16-MFMA GEMM (unchanged from round 1, correct & ~100us combined)
// ---------------------------------------------------------------------------
template<int MODE>
__global__ __launch_bounds__(256)
void gemm_kernel(const float* __restrict__ A, const float* __restrict__ B,
                 const float* __restrict__ bias,
                 float* __restrict__ out0, float* __restrict__ out1,
                 float* __restrict__ out2,
                 int M, int N, int K,
                 const float* __restrict__ scp, const float* __restrict__ zpp)
{
    __shared__ __bf16 Asm[128][40];
    __shared__ __bf16 Bsm[128][40];   // transposed: [n][k]

    const int tid  = threadIdx.x;
    const int m0   = blockIdx.y * 128;
    const int n0   = blockIdx.x * 128;
    const int w    = tid >> 6, lane = tid & 63;
    const int wm   = (w & 1) * 64, wn = (w >> 1) * 64;
    const int r16  = lane & 15, quad = lane >> 4;

    f32x4 acc[4][4];
    #pragma unroll
    for (int i = 0; i < 4; i++)
        #pragma unroll
        for (int j = 0; j < 4; j++) acc[i][j] = 0.f;

    for (int k0 = 0; k0 < K; k0 += 32) {
        #pragma unroll
        for (int i = 0; i < 4; i++) {
            int id  = tid + i * 256;
            int row = id >> 3, c = id & 7;
            f32x4 v = *(const f32x4*)&A[(size_t)(m0 + row) * K + k0 + c * 4];
            bf16x4 bv;
            bv.x = (__bf16)v.x; bv.y = (__bf16)v.y;
            bv.z = (__bf16)v.z; bv.w = (__bf16)v.w;
            *(bf16x4*)&Asm[row][c * 4] = bv;
        }
        #pragma unroll
        for (int i = 0; i < 4; i++) {
            int id = tid + i * 256;
            int n  = id & 127, kc = id >> 7;
            float f0 = B[(size_t)(k0 + kc * 4 + 0) * N + n0 + n];
            float f1 = B[(size_t)(k0 + kc * 4 + 1) * N + n0 + n];
            float f2 = B[(size_t)(k0 + kc * 4 + 2) * N + n0 + n];
            float f3 = B[(size_t)(k0 + kc * 4 + 3) * N + n0 + n];
            bf16x4 bv;
            bv.x = (__bf16)f0; bv.y = (__bf16)f1;
            bv.z = (__bf16)f2; bv.w = (__bf16)f3;
            *(bf16x4*)&Bsm[n][kc * 4] = bv;
        }
        __syncthreads();

        bf16x8 af[4], bfr[4];
        #pragma unroll
        for (int mt = 0; mt < 4; mt++)
            af[mt] = *(const bf16x8*)&Asm[wm + mt * 16 + r16][quad * 8];
        #pragma unroll
        for (int nt = 0; nt < 4; nt++)
            bfr[nt] = *(const bf16x8*)&Bsm[wn + nt * 16 + r16][quad * 8];
        #pragma unroll
        for (int mt = 0; mt < 4; mt++)
            #pragma unroll
            for (int nt = 0; nt < 4; nt++)
                acc[mt][nt] = __builtin_amdgcn_mfma_f32_16x16x32_bf16(
                    af[mt], bfr[nt], acc[mt][nt], 0, 0, 0);
        __syncthreads();
    }

    const float sc = scp[0];
    const float zp = zpp[0];

    #pragma unroll
    for (int mt = 0; mt < 4; mt++) {
        #pragma unroll
        for (int nt = 0; nt < 4; nt++) {
            #pragma unroll
            for (int r = 0; r < 4; r++) {
                int gm = m0 + wm + mt * 16 + quad * 4 + r;
                int gn = n0 + wn + nt * 16 + r16;
                float val = acc[mt][nt][r] + bias[gn];
                if (MODE == 1) {
                    out0[(size_t)gm * N + gn] = val;
                } else {
                    int part = gn >> 10;
                    int idx  = gn & 1023;
                    int h = idx >> 6, d = idx & 63;
                    int b = gm >> 11, t = gm & 2047;
                    size_t off = (((size_t)(b * NH + h)) * TB + t) * HD + d;
                    if (part == 0) {
                        out0[off] = val;
                    } else {
                        float qv = val / sc + zp;
                        qv = rintf(qv);
                        qv = fminf(fmaxf(qv, 0.f), 255.f);
                        float dq = (qv - zp) * sc;
                        if (part == 1) out1[off] = dq;
                        else           out2[off] = dq;
                    }
                }
            }
        }
    }
}

// ---------------------------------------------------------------------------
// MFMA flash attention (bf16 QK^T and PV, fp32 softmax).
// Block = 256 threads (4 waves), 64 q-rows/block (16 per wave), 64-key tiles.
// Grid = 32 q-tiles (big first) x 32 (b,h) = 1024 blocks.
// Ksm[key][d] feeds QK^T B-frags; Vsm[d][key] (transposed, conflict-free
// key-major staging writes) feeds PV B-frags; P goes C-layout -> LDS ->
// A-layout per wave (m120-verified round trip).
// ---------------------------------------------------------------------------
__global__ __launch_bounds__(256)
void attn_mfma(const float* __restrict__ Q, const float* __restrict__ Kg,
               const float* __restrict__ Vg, float* __restrict__ O)
{
    __shared__ alignas(16) __bf16 Ksm[64][72];
    __shared__ alignas(16) __bf16 Vsm[64][72];   // [d][key]
    __shared__ alignas(16) __bf16 Psm[4][16][72];

    const int tid  = threadIdx.x;
    const int qt   = 31 - (blockIdx.x >> 5);     // heavy q-tiles dispatch first
    const int bh   = blockIdx.x & 31;
    const int q0   = qt * 64;
    const int w    = tid >> 6, lane = tid & 63;
    const int l15  = lane & 15, quad = lane >> 4;
    const int b    = bh >> 4, h = bh & 15;

    const float cs = 0.125f * 1.44269504f;       // 1/sqrt(64) * log2(e)

    // Q fragments (A-layout), pre-scaled so softmax is pure exp2
    const float* Qrow = Q + ((size_t)bh * TB + q0 + w * 16 + l15) * HD;
    bf16x8 qf[2];
    #pragma unroll
    for (int ks = 0; ks < 2; ks++) {
        f32x4 a  = *(const f32x4*)&Qrow[ks * 32 + quad * 8];
        f32x4 c4 = *(const f32x4*)&Qrow[ks * 32 + quad * 8 + 4];
        bf16x8 f;
        f[0] = (__bf16)(a.x * cs);  f[1] = (__bf16)(a.y * cs);
        f[2] = (__bf16)(a.z * cs);  f[3] = (__bf16)(a.w * cs);
        f[4] = (__bf16)(c4.x * cs); f[5] = (__bf16)(c4.y * cs);
        f[6] = (__bf16)(c4.z * cs); f[7] = (__bf16)(c4.w * cs);
        qf[ks] = f;
    }

    f32x4 acc_o[4];
    #pragma unroll
    for (int nt = 0; nt < 4; nt++) acc_o[nt] = 0.f;
    f32x4 mrun, lrun;
    #pragma unroll
    for (int r = 0; r < 4; r++) { mrun[r] = -3.0e38f; lrun[r] = 0.f; }

    const float* Kbh = Kg + (size_t)bh * TB * HD;
    const float* Vbh = Vg + (size_t)bh * TB * HD;

    for (int kt = 0; kt <= qt; kt++) {
        __syncthreads();   // previous tile's LDS reads done before overwrite
        // ---- stage K [key][d], coalesced reads, conflict-free b64 writes
        #pragma unroll
        for (int i = 0; i < 4; i++) {
            int id = tid + i * 256;
            int key = id >> 4, c = id & 15;
            f32x4 v = *(const f32x4*)&Kbh[(size_t)(kt * 64 + key) * HD + c * 4];
            bf16x4 bv;
            bv.x = (__bf16)v.x; bv.y = (__bf16)v.y;
            bv.z = (__bf16)v.z; bv.w = (__bf16)v.w;
            *(bf16x4*)&Ksm[key][c * 4] = bv;
        }
        // ---- stage V transposed [d][key]; key-major lanes -> b16 writes
        //      hit all 32 banks (2-way, free); reads are L1/L2-resident
        #pragma unroll
        for (int i = 0; i < 4; i++) {
            int id = tid + i * 256;
            int key = id & 63;
            int c = id >> 6;                       // 0..15 across waves/iters
            f32x4 v = *(const f32x4*)&Vbh[(size_t)(kt * 64 + key) * HD + c * 4];
            Vsm[c * 4 + 0][key] = (__bf16)v.x;
            Vsm[c * 4 + 1][key] = (__bf16)v.y;
            Vsm[c * 4 + 2][key] = (__bf16)v.z;
            Vsm[c * 4 + 3][key] = (__bf16)v.w;
        }
        __syncthreads();

        const bool diag = (kt == qt);

        // ---- S = Q K^T (scaled): 8 MFMAs (skip fully-masked n-tiles on diag)
        f32x4 s[4];
        #pragma unroll
        for (int nt = 0; nt < 4; nt++) s[nt] = 0.f;
        #pragma unroll
        for (int nt = 0; nt < 4; nt++) {
            if (diag && nt > w) continue;          // block/wave-uniform
            #pragma unroll
            for (int ks = 0; ks < 2; ks++) {
                bf16x8 kf = *(const bf16x8*)&Ksm[nt * 16 + l15][ks * 32 + quad * 8];
                s[nt] = __builtin_amdgcn_mfma_f32_16x16x32_bf16(qf[ks], kf, s[nt], 0, 0, 0);
            }
        }

        // ---- causal mask on the diagonal tile
        const int rowb = w * 16 + quad * 4;        // local row base
        if (diag) {
            #pragma unroll
            for (int nt = 0; nt < 4; nt++) {
                int keyl = nt * 16 + l15;
                #pragma unroll
                for (int r = 0; r < 4; r++)
                    if (keyl > rowb + r) s[nt][r] = -3.0e38f;
            }
        }

        // ---- online softmax (rows live across 16 lanes of each quad-group)
        f32x4 mx = s[0];
        #pragma unroll
        for (int nt = 1; nt < 4; nt++)
            #pragma unroll
            for (int r = 0; r < 4; r++) mx[r] = fmaxf(mx[r], s[nt][r]);
        #pragma unroll
        for (int mk = 1; mk < 16; mk <<= 1)
            #pragma unroll
            for (int r = 0; r < 4; r++)
                mx[r] = fmaxf(mx[r], __shfl_xor(mx[r], mk));

        f32x4 mnew, alpha;
        #pragma unroll
        for (int r = 0; r < 4; r++) {
            mnew[r]  = fmaxf(mrun[r], mx[r]);
            alpha[r] = exp2fast(mrun[r] - mnew[r]);
        }
        #pragma unroll
        for (int nt = 0; nt < 4; nt++)
            #pragma unroll
            for (int r = 0; r < 4; r++) acc_o[nt][r] *= alpha[r];

        f32x4 ls;
        #pragma unroll
        for (int r = 0; r < 4; r++) ls[r] = 0.f;
        #pragma unroll
        for (int nt = 0; nt < 4; nt++)
            #pragma unroll
            for (int r = 0; r < 4; r++) {
                float p = exp2fast(s[nt][r] - mnew[r]);
                s[nt][r] = p;
                ls[r] += p;
            }
        #pragma unroll
        for (int mk = 1; mk < 16; mk <<= 1)
            #pragma unroll
            for (int r = 0; r < 4; r++) ls[r] += __shfl_xor(ls[r], mk);
        #pragma unroll
        for (int r = 0; r < 4; r++) lrun[r] = lrun[r] * alpha[r] + ls[r];
        mrun = mnew;

        // ---- P: C-layout regs -> per-wave LDS -> A-layout frags
        #pragma unroll
        for (int nt = 0; nt < 4; nt++)
            #pragma unroll
            for (int r = 0; r < 4; r++)
                Psm[w][quad * 4 + r][nt * 16 + l15] = (__bf16)s[nt][r];
        asm volatile("s_waitcnt lgkmcnt(0)" ::: "memory");  // wave-local order

        bf16x8 pf0 = *(const bf16x8*)&Psm[w][l15][quad * 8];
        bf16x8 pf1 = *(const bf16x8*)&Psm[w][l15][32 + quad * 8];
        #pragma unroll
        for (int nt = 0; nt < 4; nt++) {
            bf16x8 vf0 = *(const bf16x8*)&Vsm[nt * 16 + l15][quad * 8];
            bf16x8 vf1 = *(const bf16x8*)&Vsm[nt * 16 + l15][32 + quad * 8];
            acc_o[nt] = __builtin_amdgcn_mfma_f32_16x16x32_bf16(pf0, vf0, acc_o[nt], 0, 0, 0);
            acc_o[nt] = __builtin_amdgcn_mfma_f32_16x16x32_bf16(pf1, vf1, acc_o[nt], 0, 0, 0);
        }
    }

    // ---- epilogue: normalize, store [B,T,C]
    f32x4 inv;
    #pragma unroll
    for (int r = 0; r < 4; r++) inv[r] = 1.f / lrun[r];
    #pragma unroll
    for (int nt = 0; nt < 4; nt++)
        #pragma unroll
        for (int r = 0; r < 4; r++) {
            size_t row = (size_t)(b * TB) + q0 + w * 16 + quad * 4 + r;
            O[row * CC + h * HD + nt * 16 + l15] = acc_o[nt][r] * inv[r];
        }
}

extern "C" void kernel_launch(void* const* d_in, const int* in_sizes, int n_in,
                              void* d_out, int out_size, void* d_ws, size_t ws_size,
                              hipStream_t stream) {
    (void)in_sizes; (void)n_in; (void)out_size; (void)ws_size;
    const float* hidden   = (const float*)d_in[0];
    const float* W_attn   = (const float*)d_in[1];
    const float* b_attn   = (const float*)d_in[2];
    const float* W_proj   = (const float*)d_in[3];
    const float* b_proj   = (const float*)d_in[4];
    const float* kv_scale = (const float*)d_in[5];
    const float* kv_zp    = (const float*)d_in[6];
    float* out = (float*)d_out;

    float* qws = (float*)d_ws;
    float* kws = qws + (size_t)2 * NH * TB * HD;
    float* vws = kws + (size_t)2 * NH * TB * HD;
    float* ows = vws + (size_t)2 * NH * TB * HD;

    gemm_kernel<0><<<dim3(3072 / 128, 4096 / 128), 256, 0, stream>>>(
        hidden, W_attn, b_attn, qws, kws, vws, 4096, 3072, 1024, kv_scale, kv_zp);

    attn_mfma<<<dim3(32 * 32), 256, 0, stream>>>(qws, kws, vws, ows);

    gemm_kernel<1><<<dim3(1024 / 128, 4096 / 128), 256, 0, stream>>>(
        ows, W_proj, b_proj, out, nullptr, nullptr, 4096, 1024, 1024, kv_scale, kv_zp);
}

// Round 3
// 221.848 us; speedup vs baseline: 6.4092x; 1.2984x over previous
//
#include <hip/hip_runtime.h>
#include <math.h>

#define TB 2048
#define CC 1024
#define NH 16
#define HD 64

typedef __bf16 bf16x8 __attribute__((ext_vector_type(8)));
typedef __bf16 bf16x4 __attribute__((ext_vector_type(4)));
typedef float  f32x4  __attribute__((ext_vector_type(4)));

__device__ inline float exp2fast(float x) { return __builtin_amdgcn_exp2f(x); }

// async global->LDS, 16B per lane; LDS dest = wave-uniform base + lane*16
__device__ __forceinline__ void gl_lds16(const __bf16* g, __bf16* l) {
    __builtin_amdgcn_global_load_lds(
        (const __attribute__((address_space(1))) void*)g,
        (__attribute__((address_space(3))) void*)l, 16, 0, 0);
}

// ---------------------------------------------------------------------------
// fp32 -> bf16 straight convert (hidden_states)
// ---------------------------------------------------------------------------
__global__ __launch_bounds__(256)
void cvt_kernel(const float* __restrict__ src, __bf16* __restrict__ dst) {
    int i = (blockIdx.x * 256 + threadIdx.x) * 4;
    f32x4 v = *(const f32x4*)&src[i];
    bf16x4 o;
    o.x = (__bf16)v.x; o.y = (__bf16)v.y; o.z = (__bf16)v.z; o.w = (__bf16)v.w;
    *(bf16x4*)&dst[i] = o;
}

// ---------------------------------------------------------------------------
// fp32 [K][N] -> bf16 [N][K] tiled transpose (weights, one-time)
// ---------------------------------------------------------------------------
__global__ __launch_bounds__(256)
void tpose_kernel(const float* __restrict__ src, __bf16* __restrict__ dst,
                  int K, int N) {
    __shared__ __bf16 L[64][68];
    const int tid = threadIdx.x;
    const int n0 = blockIdx.x * 64, k0 = blockIdx.y * 64;
    #pragma unroll
    for (int i = 0; i < 4; i++) {
        int id = tid + i * 256;
        int r = id >> 4, c = (id & 15) * 4;
        f32x4 v = *(const f32x4*)&src[(size_t)(k0 + r) * N + n0 + c];
        bf16x4 o;
        o.x = (__bf16)v.x; o.y = (__bf16)v.y; o.z = (__bf16)v.z; o.w = (__bf16)v.w;
        *(bf16x4*)&L[r][c] = o;
    }
    __syncthreads();
    #pragma unroll
    for (int i = 0; i < 4; i++) {
        int id = tid + i * 256;
        int nr = id >> 4, kc = (id & 15) * 4;
        bf16x4 o;
        o.x = L[kc + 0][nr]; o.y = L[kc + 1][nr];
        o.z = L[kc + 2][nr]; o.w = L[kc + 3][nr];
        *(bf16x4*)&dst[(size_t)(n0 + nr) * K + k0 + kc] = o;
    }
}

// ---------------------------------------------------------------------------
// m97-style bf16 GEMM, B pre-transposed [N][K]. Tile 128 x BN, BK=32.
// Unpadded LDS (global_load_lds lane-linear layout); b128 frag reads hit the
// 8-cycle minimum (stride 64B rows). MODE 0: bias+split+fake-quant -> bf16
// q/k/v [B,H,T,D]. MODE 1: bias -> fp32 row-major.
// ---------------------------------------------------------------------------
template<int BN, int MODE>
__global__ __launch_bounds__(256)
void gemm_bt(const __bf16* __restrict__ A, const __bf16* __restrict__ Bt,
             const float* __restrict__ bias,
             __bf16* __restrict__ o0, __bf16* __restrict__ o1,
             __bf16* __restrict__ o2, float* __restrict__ of,
             int M, int N, int K,
             const float* __restrict__ scp, const float* __restrict__ zpp)
{
    constexpr int NT = BN / 32;            // n-frags per wave
    __shared__ __bf16 Asm[128][32];
    __shared__ __bf16 Bsm[BN][32];

    const int tid  = threadIdx.x;
    const int m0   = blockIdx.y * 128;
    const int n0   = blockIdx.x * BN;
    const int w    = tid >> 6, lane = tid & 63;
    const int wm   = (w & 1) * 64, wn = (w >> 1) * (BN / 2);
    const int r16  = lane & 15, quad = lane >> 4;
    const int srow = lane >> 2, scol = (lane & 3) * 8;   // staging: 16 rows/wave

    f32x4 acc[4][NT];
    #pragma unroll
    for (int i = 0; i < 4; i++)
        #pragma unroll
        for (int j = 0; j < NT; j++) acc[i][j] = 0.f;

    for (int k0 = 0; k0 < K; k0 += 32) {
        #pragma unroll
        for (int p = 0; p < 2; p++)
            gl_lds16(&A[(size_t)(m0 + p * 64 + w * 16 + srow) * K + k0 + scol],
                     &Asm[p * 64 + w * 16][0]);
        #pragma unroll
        for (int p = 0; p < BN / 64; p++)
            gl_lds16(&Bt[(size_t)(n0 + p * 64 + w * 16 + srow) * K + k0 + scol],
                     &Bsm[p * 64 + w * 16][0]);
        __syncthreads();   // drains vmcnt -> DMA complete

        bf16x8 af[4], bfr[NT];
        #pragma unroll
        for (int mt = 0; mt < 4; mt++)
            af[mt] = *(const bf16x8*)&Asm[wm + mt * 16 + r16][quad * 8];
        #pragma unroll
        for (int nt = 0; nt < NT; nt++)
            bfr[nt] = *(const bf16x8*)&Bsm[wn + nt * 16 + r16][quad * 8];
        #pragma unroll
        for (int mt = 0; mt < 4; mt++)
            #pragma unroll
            for (int nt = 0; nt < NT; nt++)
                acc[mt][nt] = __builtin_amdgcn_mfma_f32_16x16x32_bf16(
                    af[mt], bfr[nt], acc[mt][nt], 0, 0, 0);
        __syncthreads();
    }

    const float sc = scp[0];
    const float zp = zpp[0];

    #pragma unroll
    for (int mt = 0; mt < 4; mt++) {
        #pragma unroll
        for (int nt = 0; nt < NT; nt++) {
            #pragma unroll
            for (int r = 0; r < 4; r++) {
                int gm = m0 + wm + mt * 16 + quad * 4 + r;
                int gn = n0 + wn + nt * 16 + r16;
                float val = acc[mt][nt][r] + bias[gn];
                if (MODE == 1) {
                    of[(size_t)gm * N + gn] = val;
                } else {
                    int part = gn >> 10;
                    int idx  = gn & 1023;
                    int h = idx >> 6, d = idx & 63;
                    int b = gm >> 11, t = gm & 2047;
                    size_t off = (((size_t)(b * NH + h)) * TB + t) * HD + d;
                    if (part == 0) {
                        o0[off] = (__bf16)val;
                    } else {
                        float qv = val / sc + zp;
                        qv = rintf(qv);                 // half-to-even like jnp.round
                        qv = fminf(fmaxf(qv, 0.f), 255.f);
                        float dq = (qv - zp) * sc;
                        if (part == 1) o1[off] = (__bf16)dq;
                        else           o2[off] = (__bf16)dq;
                    }
                }
            }
        }
    }
}

// ---------------------------------------------------------------------------
// MFMA flash attention, bf16 in/out. 64 q-rows/block (4 waves x 16),
// 64-key tiles, scores scaled post-MFMA, online softmax in registers,
// P via per-wave LDS round-trip (C-layout -> A-layout).
// ---------------------------------------------------------------------------
__global__ __launch_bounds__(256)
void attn_mfma(const __bf16* __restrict__ Q, const __bf16* __restrict__ Kg,
               const __bf16* __restrict__ Vg, __bf16* __restrict__ O)
{
    __shared__ alignas(16) __bf16 Ksm[64][72];
    __shared__ alignas(16) __bf16 Vsm[64][72];   // [d][key]
    __shared__ alignas(16) __bf16 Psm[4][16][72];

    const int tid  = threadIdx.x;
    const int qt   = 31 - (blockIdx.x >> 5);     // heavy q-tiles first
    const int bh   = blockIdx.x & 31;
    const int q0   = qt * 64;
    const int w    = tid >> 6, lane = tid & 63;
    const int l15  = lane & 15, quad = lane >> 4;
    const int b    = bh >> 4, h = bh & 15;

    const float cs = 0.125f * 1.44269504f;       // 1/sqrt(64) * log2(e)

    const __bf16* Qrow = Q + ((size_t)bh * TB + q0 + w * 16 + l15) * HD;
    bf16x8 qf[2];
    qf[0] = *(const bf16x8*)&Qrow[quad * 8];
    qf[1] = *(const bf16x8*)&Qrow[32 + quad * 8];

    f32x4 acc_o[4];
    #pragma unroll
    for (int nt = 0; nt < 4; nt++) acc_o[nt] = 0.f;
    f32x4 mrun, lrun;
    #pragma unroll
    for (int r = 0; r < 4; r++) { mrun[r] = -3.0e38f; lrun[r] = 0.f; }

    const __bf16* Kbh = Kg + (size_t)bh * TB * HD;
    const __bf16* Vbh = Vg + (size_t)bh * TB * HD;

    for (int kt = 0; kt <= qt; kt++) {
        __syncthreads();   // prior tile's LDS reads done before overwrite
        #pragma unroll
        for (int i = 0; i < 2; i++) {
            int id = tid + i * 256;
            int row = id >> 3, c = id & 7;
            *(bf16x8*)&Ksm[row][c * 8] =
                *(const bf16x8*)&Kbh[(size_t)(kt * 64 + row) * HD + c * 8];
        }
        #pragma unroll
        for (int i = 0; i < 2; i++) {
            int id = tid + i * 256;
            int key = id & 63, c = id >> 6;       // c in [0,8)
            bf16x8 v = *(const bf16x8*)&Vbh[(size_t)(kt * 64 + key) * HD + c * 8];
            #pragma unroll
            for (int j = 0; j < 8; j++) Vsm[c * 8 + j][key] = v[j];
        }
        __syncthreads();

        const bool diag = (kt == qt);

        f32x4 s[4];
        #pragma unroll
        for (int nt = 0; nt < 4; nt++) s[nt] = 0.f;
        #pragma unroll
        for (int nt = 0; nt < 4; nt++) {
            if (diag && nt > w) continue;          // wave-uniform skip
            #pragma unroll
            for (int ks = 0; ks < 2; ks++) {
                bf16x8 kf = *(const bf16x8*)&Ksm[nt * 16 + l15][ks * 32 + quad * 8];
                s[nt] = __builtin_amdgcn_mfma_f32_16x16x32_bf16(qf[ks], kf, s[nt], 0, 0, 0);
            }
        }
        #pragma unroll
        for (int nt = 0; nt < 4; nt++)
            #pragma unroll
            for (int r = 0; r < 4; r++) s[nt][r] *= cs;

        const int rowb = w * 16 + quad * 4;
        if (diag) {
            #pragma unroll
            for (int nt = 0; nt < 4; nt++) {
                int keyl = nt * 16 + l15;
                #pragma unroll
                for (int r = 0; r < 4; r++)
                    if (keyl > rowb + r) s[nt][r] = -3.0e38f;
            }
        }

        f32x4 mx = s[0];
        #pragma unroll
        for (int nt = 1; nt < 4; nt++)
            #pragma unroll
            for (int r = 0; r < 4; r++) mx[r] = fmaxf(mx[r], s[nt][r]);
        #pragma unroll
        for (int mk = 1; mk < 16; mk <<= 1)
            #pragma unroll
            for (int r = 0; r < 4; r++)
                mx[r] = fmaxf(mx[r], __shfl_xor(mx[r], mk));

        f32x4 mnew, alpha;
        #pragma unroll
        for (int r = 0; r < 4; r++) {
            mnew[r]  = fmaxf(mrun[r], mx[r]);
            alpha[r] = exp2fast(mrun[r] - mnew[r]);
        }
        #pragma unroll
        for (int nt = 0; nt < 4; nt++)
            #pragma unroll
            for (int r = 0; r < 4; r++) acc_o[nt][r] *= alpha[r];

        f32x4 ls;
        #pragma unroll
        for (int r = 0; r < 4; r++) ls[r] = 0.f;
        #pragma unroll
        for (int nt = 0; nt < 4; nt++)
            #pragma unroll
            for (int r = 0; r < 4; r++) {
                float p = exp2fast(s[nt][r] - mnew[r]);
                s[nt][r] = p;
                ls[r] += p;
            }
        #pragma unroll
        for (int mk = 1; mk < 16; mk <<= 1)
            #pragma unroll
            for (int r = 0; r < 4; r++) ls[r] += __shfl_xor(ls[r], mk);
        #pragma unroll
        for (int r = 0; r < 4; r++) lrun[r] = lrun[r] * alpha[r] + ls[r];
        mrun = mnew;

        #pragma unroll
        for (int nt = 0; nt < 4; nt++)
            #pragma unroll
            for (int r = 0; r < 4; r++)
                Psm[w][quad * 4 + r][nt * 16 + l15] = (__bf16)s[nt][r];
        asm volatile("s_waitcnt lgkmcnt(0)" ::: "memory");  // wave-local order

        bf16x8 pf0 = *(const bf16x8*)&Psm[w][l15][quad * 8];
        bf16x8 pf1 = *(const bf16x8*)&Psm[w][l15][32 + quad * 8];
        #pragma unroll
        for (int nt = 0; nt < 4; nt++) {
            bf16x8 vf0 = *(const bf16x8*)&Vsm[nt * 16 + l15][quad * 8];
            bf16x8 vf1 = *(const bf16x8*)&Vsm[nt * 16 + l15][32 + quad * 8];
            acc_o[nt] = __builtin_amdgcn_mfma_f32_16x16x32_bf16(pf0, vf0, acc_o[nt], 0, 0, 0);
            acc_o[nt] = __builtin_amdgcn_mfma_f32_16x16x32_bf16(pf1, vf1, acc_o[nt], 0, 0, 0);
        }
    }

    f32x4 inv;
    #pragma unroll
    for (int r = 0; r < 4; r++) inv[r] = 1.f / lrun[r];
    #pragma unroll
    for (int nt = 0; nt < 4; nt++)
        #pragma unroll
        for (int r = 0; r < 4; r++) {
            size_t row = (size_t)(b * TB) + q0 + w * 16 + quad * 4 + r;
            O[row * CC + h * HD + nt * 16 + l15] = (__bf16)(acc_o[nt][r] * inv[r]);
        }
}

extern "C" void kernel_launch(void* const* d_in, const int* in_sizes, int n_in,
                              void* d_out, int out_size, void* d_ws, size_t ws_size,
                              hipStream_t stream) {
    (void)in_sizes; (void)n_in; (void)out_size; (void)ws_size;
    const float* hidden   = (const float*)d_in[0];
    const float* W_attn   = (const float*)d_in[1];
    const float* b_attn   = (const float*)d_in[2];
    const float* W_proj   = (const float*)d_in[3];
    const float* b_proj   = (const float*)d_in[4];
    const float* kv_scale = (const float*)d_in[5];
    const float* kv_zp    = (const float*)d_in[6];
    float* out = (float*)d_out;

    // bf16 workspace: hb 4M | wat 3M | wpt 1M | q/k/v 4M each | ows 4M = 48MB
    __bf16* hb  = (__bf16*)d_ws;
    __bf16* wat = hb  + (size_t)4096 * 1024;
    __bf16* wpt = wat + (size_t)3072 * 1024;
    __bf16* qws = wpt + (size_t)1024 * 1024;
    __bf16* kws = qws + (size_t)2 * NH * TB * HD;
    __bf16* vws = kws + (size_t)2 * NH * TB * HD;
    __bf16* ows = vws + (size_t)2 * NH * TB * HD;

    cvt_kernel<<<4096, 256, 0, stream>>>(hidden, hb);
    tpose_kernel<<<dim3(48, 16), 256, 0, stream>>>(W_attn, wat, 1024, 3072);
    tpose_kernel<<<dim3(16, 16), 256, 0, stream>>>(W_proj, wpt, 1024, 1024);

    gemm_bt<128, 0><<<dim3(24, 32), 256, 0, stream>>>(
        hb, wat, b_attn, qws, kws, vws, nullptr, 4096, 3072, 1024, kv_scale, kv_zp);

    attn_mfma<<<dim3(32 * 32), 256, 0, stream>>>(qws, kws, vws, ows);

    gemm_bt<64, 1><<<dim3(16, 32), 256, 0, stream>>>(
        ows, wpt, b_proj, nullptr, nullptr, nullptr, out, 4096, 1024, 1024,
        kv_scale, kv_zp);
}

// Round 4
// 191.206 us; speedup vs baseline: 7.4363x; 1.1603x over previous
//
#include <hip/hip_runtime.h>
#include <math.h>

#define TB 2048
#define CC 1024
#define NH 16
#define HD 64

typedef __bf16 bf16x8 __attribute__((ext_vector_type(8)));
typedef __bf16 bf16x4 __attribute__((ext_vector_type(4)));
typedef float  f32x4  __attribute__((ext_vector_type(4)));

__device__ inline float exp2fast(float x) { return __builtin_amdgcn_exp2f(x); }

// async global->LDS, 16B per lane; LDS dest = wave-uniform base + lane*16
__device__ __forceinline__ void gl_lds16(const __bf16* g, __bf16* l) {
    __builtin_amdgcn_global_load_lds(
        (const __attribute__((address_space(1))) void*)g,
        (__attribute__((address_space(3))) void*)l, 16, 0, 0);
}

// ---------------------------------------------------------------------------
// fp32 -> bf16 straight convert (hidden_states)
// ---------------------------------------------------------------------------
__global__ __launch_bounds__(256)
void cvt_kernel(const float* __restrict__ src, __bf16* __restrict__ dst) {
    int i = (blockIdx.x * 256 + threadIdx.x) * 4;
    f32x4 v = *(const f32x4*)&src[i];
    bf16x4 o;
    o.x = (__bf16)v.x; o.y = (__bf16)v.y; o.z = (__bf16)v.z; o.w = (__bf16)v.w;
    *(bf16x4*)&dst[i] = o;
}

// ---------------------------------------------------------------------------
// fp32 [K][N] -> bf16 [N][K] tiled transpose (weights, one-time)
// ---------------------------------------------------------------------------
__global__ __launch_bounds__(256)
void tpose_kernel(const float* __restrict__ src, __bf16* __restrict__ dst,
                  int K, int N) {
    __shared__ __bf16 L[64][68];
    const int tid = threadIdx.x;
    const int n0 = blockIdx.x * 64, k0 = blockIdx.y * 64;
    #pragma unroll
    for (int i = 0; i < 4; i++) {
        int id = tid + i * 256;
        int r = id >> 4, c = (id & 15) * 4;
        f32x4 v = *(const f32x4*)&src[(size_t)(k0 + r) * N + n0 + c];
        bf16x4 o;
        o.x = (__bf16)v.x; o.y = (__bf16)v.y; o.z = (__bf16)v.z; o.w = (__bf16)v.w;
        *(bf16x4*)&L[r][c] = o;
    }
    __syncthreads();
    #pragma unroll
    for (int i = 0; i < 4; i++) {
        int id = tid + i * 256;
        int nr = id >> 4, kc = (id & 15) * 4;
        bf16x4 o;
        o.x = L[kc + 0][nr]; o.y = L[kc + 1][nr];
        o.z = L[kc + 2][nr]; o.w = L[kc + 3][nr];
        *(bf16x4*)&dst[(size_t)(n0 + nr) * K + k0 + kc] = o;
    }
}

// ---------------------------------------------------------------------------
// m97-style bf16 GEMM, B pre-transposed [N][K]. Tile 128 x BN, BK=32.
// MODE 0: bias+split+fake-quant -> bf16 q/k/v [B,H,T,D]; Q pre-scaled by
// 0.125*log2(e) so attention softmax is pure exp2. MODE 1: bias -> fp32.
// ---------------------------------------------------------------------------
template<int BN, int MODE>
__global__ __launch_bounds__(256)
void gemm_bt(const __bf16* __restrict__ A, const __bf16* __restrict__ Bt,
             const float* __restrict__ bias,
             __bf16* __restrict__ o0, __bf16* __restrict__ o1,
             __bf16* __restrict__ o2, float* __restrict__ of,
             int M, int N, int K,
             const float* __restrict__ scp, const float* __restrict__ zpp)
{
    constexpr int NT = BN / 32;
    __shared__ __bf16 Asm[128][32];
    __shared__ __bf16 Bsm[BN][32];

    const int tid  = threadIdx.x;
    const int m0   = blockIdx.y * 128;
    const int n0   = blockIdx.x * BN;
    const int w    = tid >> 6, lane = tid & 63;
    const int wm   = (w & 1) * 64, wn = (w >> 1) * (BN / 2);
    const int r16  = lane & 15, quad = lane >> 4;
    const int srow = lane >> 2, scol = (lane & 3) * 8;

    f32x4 acc[4][NT];
    #pragma unroll
    for (int i = 0; i < 4; i++)
        #pragma unroll
        for (int j = 0; j < NT; j++) acc[i][j] = 0.f;

    for (int k0 = 0; k0 < K; k0 += 32) {
        #pragma unroll
        for (int p = 0; p < 2; p++)
            gl_lds16(&A[(size_t)(m0 + p * 64 + w * 16 + srow) * K + k0 + scol],
                     &Asm[p * 64 + w * 16][0]);
        #pragma unroll
        for (int p = 0; p < BN / 64; p++)
            gl_lds16(&Bt[(size_t)(n0 + p * 64 + w * 16 + srow) * K + k0 + scol],
                     &Bsm[p * 64 + w * 16][0]);
        __syncthreads();

        bf16x8 af[4], bfr[NT];
        #pragma unroll
        for (int mt = 0; mt < 4; mt++)
            af[mt] = *(const bf16x8*)&Asm[wm + mt * 16 + r16][quad * 8];
        #pragma unroll
        for (int nt = 0; nt < NT; nt++)
            bfr[nt] = *(const bf16x8*)&Bsm[wn + nt * 16 + r16][quad * 8];
        #pragma unroll
        for (int mt = 0; mt < 4; mt++)
            #pragma unroll
            for (int nt = 0; nt < NT; nt++)
                acc[mt][nt] = __builtin_amdgcn_mfma_f32_16x16x32_bf16(
                    af[mt], bfr[nt], acc[mt][nt], 0, 0, 0);
        __syncthreads();
    }

    const float sc = scp[0];
    const float zp = zpp[0];

    #pragma unroll
    for (int mt = 0; mt < 4; mt++) {
        #pragma unroll
        for (int nt = 0; nt < NT; nt++) {
            #pragma unroll
            for (int r = 0; r < 4; r++) {
                int gm = m0 + wm + mt * 16 + quad * 4 + r;
                int gn = n0 + wn + nt * 16 + r16;
                float val = acc[mt][nt][r] + bias[gn];
                if (MODE == 1) {
                    of[(size_t)gm * N + gn] = val;
                } else {
                    int part = gn >> 10;
                    int idx  = gn & 1023;
                    int h = idx >> 6, d = idx & 63;
                    int b = gm >> 11, t = gm & 2047;
                    size_t off = (((size_t)(b * NH + h)) * TB + t) * HD + d;
                    if (part == 0) {
                        o0[off] = (__bf16)(val * 0.18033688f);  // 0.125*log2e
                    } else {
                        float qv = val / sc + zp;
                        qv = rintf(qv);                 // half-to-even
                        qv = fminf(fmaxf(qv, 0.f), 255.f);
                        float dq = (qv - zp) * sc;
                        if (part == 1) o1[off] = (__bf16)dq;
                        else           o2[off] = (__bf16)dq;
                    }
                }
            }
        }
    }
}

// ---------------------------------------------------------------------------
// Transposed-S MFMA flash attention. S^T = K.Q^T so each thread owns ONE
// q-column: scalar m/alpha, 2-shfl reductions. Key-remapped K A-frags make
// S^T C-layout == P^T B-frag layout (register-only P move). Row-sum l via
// ones-row MFMA (extra accumulator, auto-rescaled). K/V register prefetch.
// Block = 4 waves x 16 q = 64 q-rows; 64-key tiles; grid 32 qt x 32 bh.
// ---------------------------------------------------------------------------
__global__ __launch_bounds__(256, 4)
void attn_mfma(const __bf16* __restrict__ Q, const __bf16* __restrict__ Kg,
               const __bf16* __restrict__ Vg, __bf16* __restrict__ O)
{
    __shared__ alignas(16) __bf16 Ksm[64][72];   // [key][d]
    __shared__ alignas(16) __bf16 Vsm[64][72];   // [d][key]

    const int tid  = threadIdx.x;
    const int qt   = 31 - (blockIdx.x >> 5);     // heavy q-tiles first
    const int bh   = blockIdx.x & 31;
    const int q0   = qt * 64;
    const int w    = tid >> 6, lane = tid & 63;
    const int l15  = lane & 15, quad = lane >> 4;
    const int b    = bh >> 4, h = bh & 15;

    // staging geometry
    const int krow = tid >> 3;            // 0..31
    const int kseg = (tid & 7) * 8;
    const int vkey = tid & 63;
    const int vc   = tid >> 6;            // 0..3

    const __bf16* Kbh = Kg + (size_t)bh * TB * HD;
    const __bf16* Vbh = Vg + (size_t)bh * TB * HD;

    // Q as B-operand: B[d][q], q = l15 (Q was pre-scaled in the GEMM)
    const __bf16* Qrow = Q + ((size_t)bh * TB + q0 + w * 16 + l15) * HD;
    bf16x8 qf0 = *(const bf16x8*)&Qrow[quad * 8];
    bf16x8 qf1 = *(const bf16x8*)&Qrow[32 + quad * 8];

    // key-remap base: frag nt row = rbase + (nt&1)*32 + (nt>>1)*4
    const int rbase = (l15 >> 2) * 8 + (l15 & 3);

    // ones-row A frag (row 0 only) for l accumulation
    bf16x8 af_l;
    {
        __bf16 v = (l15 == 0) ? (__bf16)1.0f : (__bf16)0.0f;
        #pragma unroll
        for (int j = 0; j < 8; j++) af_l[j] = v;
    }

    f32x4 acc_o[4], acc_l;
    #pragma unroll
    for (int nt = 0; nt < 4; nt++) acc_o[nt] = 0.f;
    acc_l = 0.f;
    float mrun = -3.0e38f;

    // prefetch tile 0 into registers
    bf16x8 kpre0 = *(const bf16x8*)&Kbh[(size_t)krow * HD + kseg];
    bf16x8 kpre1 = *(const bf16x8*)&Kbh[(size_t)(32 + krow) * HD + kseg];
    bf16x8 vpre0 = *(const bf16x8*)&Vbh[(size_t)vkey * HD + vc * 8];
    bf16x8 vpre1 = *(const bf16x8*)&Vbh[(size_t)vkey * HD + (4 + vc) * 8];

    for (int kt = 0; kt <= qt; kt++) {
        __syncthreads();                  // prior tile's LDS reads complete
        *(bf16x8*)&Ksm[krow][kseg]      = kpre0;
        *(bf16x8*)&Ksm[32 + krow][kseg] = kpre1;
        #pragma unroll
        for (int j = 0; j < 8; j++) {
            Vsm[vc * 8 + j][vkey]      = vpre0[j];
            Vsm[32 + vc * 8 + j][vkey] = vpre1[j];
        }
        __syncthreads();

        if (kt < qt) {                    // prefetch next tile during compute
            const __bf16* Kn = Kbh + (size_t)(kt + 1) * 64 * HD;
            const __bf16* Vn = Vbh + (size_t)(kt + 1) * 64 * HD;
            kpre0 = *(const bf16x8*)&Kn[(size_t)krow * HD + kseg];
            kpre1 = *(const bf16x8*)&Kn[(size_t)(32 + krow) * HD + kseg];
            vpre0 = *(const bf16x8*)&Vn[(size_t)vkey * HD + vc * 8];
            vpre1 = *(const bf16x8*)&Vn[(size_t)vkey * HD + (4 + vc) * 8];
        }

        const bool diag = (kt == qt);

        // S^T = K.Q^T : rows = remapped keys, cols = q
        f32x4 s[4];
        #pragma unroll
        for (int nt = 0; nt < 4; nt++) s[nt] = 0.f;
        #pragma unroll
        for (int nt = 0; nt < 4; nt++) {
            if (diag && (nt & 1) && w < 2) continue;   // keys>=32 all masked
            int row = rbase + (nt & 1) * 32 + ((nt >> 1) << 2);
            bf16x8 kf0 = *(const bf16x8*)&Ksm[row][quad * 8];
            bf16x8 kf1 = *(const bf16x8*)&Ksm[row][32 + quad * 8];
            s[nt] = __builtin_amdgcn_mfma_f32_16x16x32_bf16(kf0, qf0, s[nt], 0, 0, 0);
            s[nt] = __builtin_amdgcn_mfma_f32_16x16x32_bf16(kf1, qf1, s[nt], 0, 0, 0);
        }

        if (diag) {          // causal mask: key_local > q_local
            #pragma unroll
            for (int nt = 0; nt < 4; nt++) {
                int koff = (nt & 1) * 32 + ((nt >> 1) << 2) + quad * 8;
                #pragma unroll
                for (int r = 0; r < 4; r++)
                    if (koff + r > w * 16 + l15) s[nt][r] = -3.0e38f;
            }
        }

        // online softmax: scalar per thread (one q-column)
        float mx = s[0][0];
        #pragma unroll
        for (int nt = 0; nt < 4; nt++)
            #pragma unroll
            for (int r = 0; r < 4; r++) mx = fmaxf(mx, s[nt][r]);
        mx = fmaxf(mx, __shfl_xor(mx, 16));
        mx = fmaxf(mx, __shfl_xor(mx, 32));

        float mnew  = fmaxf(mrun, mx);
        float alpha = exp2fast(mrun - mnew);
        mrun = mnew;
        #pragma unroll
        for (int nt = 0; nt < 4; nt++)
            #pragma unroll
            for (int r = 0; r < 4; r++) acc_o[nt][r] *= alpha;
        acc_l[0] *= alpha;

        // P = exp2(S^T - m); register-only relayout into B-frags
        float p[4][4];
        #pragma unroll
        for (int nt = 0; nt < 4; nt++)
            #pragma unroll
            for (int r = 0; r < 4; r++) p[nt][r] = exp2fast(s[nt][r] - mnew);

        bf16x8 pf0, pf1;
        #pragma unroll
        for (int j = 0; j < 4; j++) {
            pf0[j]     = (__bf16)p[0][j];
            pf0[4 + j] = (__bf16)p[2][j];
            pf1[j]     = (__bf16)p[1][j];
            pf1[4 + j] = (__bf16)p[3][j];
        }

        // l-row via MFMA (free pipe)
        acc_l = __builtin_amdgcn_mfma_f32_16x16x32_bf16(af_l, pf0, acc_l, 0, 0, 0);
        acc_l = __builtin_amdgcn_mfma_f32_16x16x32_bf16(af_l, pf1, acc_l, 0, 0, 0);

        // O^T += V^T . P^T
        #pragma unroll
        for (int nt = 0; nt < 4; nt++) {
            bf16x8 vf0 = *(const bf16x8*)&Vsm[nt * 16 + l15][quad * 8];
            bf16x8 vf1 = *(const bf16x8*)&Vsm[nt * 16 + l15][32 + quad * 8];
            acc_o[nt] = __builtin_amdgcn_mfma_f32_16x16x32_bf16(vf0, pf0, acc_o[nt], 0, 0, 0);
            acc_o[nt] = __builtin_amdgcn_mfma_f32_16x16x32_bf16(vf1, pf1, acc_o[nt], 0, 0, 0);
        }
    }

    // epilogue: l lives in lanes 0..15 (row 0), broadcast by q-column
    float lall = __shfl(acc_l[0], l15);
    float inv  = 1.f / lall;
    size_t trow = (size_t)(b * TB) + q0 + w * 16 + l15;
    #pragma unroll
    for (int nt = 0; nt < 4; nt++) {
        bf16x4 st;
        #pragma unroll
        for (int r = 0; r < 4; r++) st[r] = (__bf16)(acc_o[nt][r] * inv);
        *(bf16x4*)&O[trow * CC + h * HD + nt * 16 + quad * 4] = st;
    }
}

extern "C" void kernel_launch(void* const* d_in, const int* in_sizes, int n_in,
                              void* d_out, int out_size, void* d_ws, size_t ws_size,
                              hipStream_t stream) {
    (void)in_sizes; (void)n_in; (void)out_size; (void)ws_size;
    const float* hidden   = (const float*)d_in[0];
    const float* W_attn   = (const float*)d_in[1];
    const float* b_attn   = (const float*)d_in[2];
    const float* W_proj   = (const float*)d_in[3];
    const float* b_proj   = (const float*)d_in[4];
    const float* kv_scale = (const float*)d_in[5];
    const float* kv_zp    = (const float*)d_in[6];
    float* out = (float*)d_out;

    __bf16* hb  = (__bf16*)d_ws;
    __bf16* wat = hb  + (size_t)4096 * 1024;
    __bf16* wpt = wat + (size_t)3072 * 1024;
    __bf16* qws = wpt + (size_t)1024 * 1024;
    __bf16* kws = qws + (size_t)2 * NH * TB * HD;
    __bf16* vws = kws + (size_t)2 * NH * TB * HD;
    __bf16* ows = vws + (size_t)2 * NH * TB * HD;

    cvt_kernel<<<4096, 256, 0, stream>>>(hidden, hb);
    tpose_kernel<<<dim3(48, 16), 256, 0, stream>>>(W_attn, wat, 1024, 3072);
    tpose_kernel<<<dim3(16, 16), 256, 0, stream>>>(W_proj, wpt, 1024, 1024);

    gemm_bt<128, 0><<<dim3(24, 32), 256, 0, stream>>>(
        hb, wat, b_attn, qws, kws, vws, nullptr, 4096, 3072, 1024, kv_scale, kv_zp);

    attn_mfma<<<dim3(32 * 32), 256, 0, stream>>>(qws, kws, vws, ows);

    gemm_bt<64, 1><<<dim3(16, 32), 256, 0, stream>>>(
        ows, wpt, b_proj, nullptr, nullptr, nullptr, out, 4096, 1024, 1024,
        kv_scale, kv_zp);
}